// Round 2
// baseline (443.887 us; speedup 1.0000x reference)
//
#include <hip/hip_runtime.h>

static constexpr int kD = 128;
static constexpr int kHedges = 20000;

// Coarse partition: edge by h>>7 (128 hedges/bucket), node by n>>9 (512 nodes/bucket)
static constexpr int kNCE = 157;      // ceil(20000/128)
static constexpr int kCapCE = 11264;  // mean 10240 + 10 sigma
static constexpr int kNCN = 196;      // ceil(100000/512)
static constexpr int kCapCN = 9216;   // mean 8192 + 11 sigma
// gather slice caps
static constexpr int kSliceE3 = 3072; // 32 hedges/block: mean 2560 + 10 sigma
static constexpr int kSliceN = 768;   // 32 nodes/block: mean 512 + 11 sigma
// partition block-local staging capacity (per_block = ceil(n_pairs/grid) must be <= this)
static constexpr int kPmax = 3200;

__device__ __forceinline__ float u2f(unsigned u) { return __uint_as_float(u); }
__device__ __forceinline__ unsigned f2u(float f) { return __float_as_uint(f); }

// round-to-nearest-even fp32 -> bf16, pack two into one uint
__device__ __forceinline__ unsigned bfpack(float x, float y) {
  unsigned ux = f2u(x); ux = (ux + 0x7FFFu + ((ux >> 16) & 1u)) >> 16;
  unsigned uy = f2u(y); uy = (uy + 0x7FFFu + ((uy >> 16) & 1u)) & 0xFFFF0000u;
  return ux | uy;
}

// ---------- L1: convert feats (fused) + partition pairs into coarse buckets ----------
// block-local counting-sort placement in LDS, then coalesced per-bucket run
// writeback (full-line stores from a single XCD) instead of per-pair 4B scatter.
__global__ __launch_bounds__(256) void partition_coarse(
    const float* __restrict__ feat, unsigned* __restrict__ feat_bf, int n_feat,
    const int* __restrict__ node_idx, const int* __restrict__ hedge_idx,
    int n_pairs,
    int* __restrict__ gcnt_e, int* __restrict__ buf_e,
    int* __restrict__ gcnt_n, int* __restrict__ buf_n) {
  __shared__ unsigned lbuf_e[kPmax];          // 12.8 KB
  __shared__ unsigned lbuf_n[kPmax];          // 12.8 KB
  __shared__ int he[kNCE], se[kNCE];          // cur counter / global shift (edge)
  __shared__ int hn[kNCN], sn_[kNCN];         // cur counter / global shift (node)
  __shared__ int wtot[4];
  const int tid = threadIdx.x;
  // fused feature conversion (grid-stride over uint4 groups of 8 floats)
  {
    const int n8 = n_feat >> 3;
    for (int t = blockIdx.x * 256 + tid; t < n8; t += gridDim.x * 256) {
      long long i = (long long)t * 8;
      const float4 v0 = *(const float4*)(feat + i);
      const float4 v1 = *(const float4*)(feat + i + 4);
      uint4 o;
      o.x = bfpack(v0.x, v0.y); o.y = bfpack(v0.z, v0.w);
      o.z = bfpack(v1.x, v1.y); o.w = bfpack(v1.z, v1.w);
      *(uint4*)(feat_bf + (i >> 1)) = o;
    }
  }
  const int per_block = (n_pairs + gridDim.x - 1) / gridDim.x;
  const int s = blockIdx.x * per_block;
  const int e = min(s + per_block, n_pairs);
  const int cnt = max(e - s, 0);              // <= kPmax by grid sizing
  for (int i = tid; i < kNCE; i += 256) he[i] = 0;
  for (int i = tid; i < kNCN; i += 256) hn[i] = 0;
  __syncthreads();
  // pass 1: local histograms for both keyings
  for (int i = s + tid; i < e; i += 256) {
    atomicAdd(&he[hedge_idx[i] >> 7], 1);
    atomicAdd(&hn[node_idx[i] >> 9], 1);
  }
  __syncthreads();
  const int lane = tid & 63, wid = tid >> 6;
  // scan edge hist (157 bins <= 256 threads): lofs = local exclusive prefix
  {
    int v = (tid < kNCE) ? he[tid] : 0;
    int x = v;
#pragma unroll
    for (int d = 1; d < 64; d <<= 1) {
      int y = __shfl_up(x, d, 64);
      if (lane >= d) x += y;
    }
    if (lane == 63) wtot[wid] = x;
    __syncthreads();
    int add = 0;
    for (int w = 0; w < wid; ++w) add += wtot[w];
    if (tid < kNCE) {
      int lofs = x + add - v;
      int base = (v > 0) ? atomicAdd(&gcnt_e[tid], v) : 0;
      se[tid] = base - lofs;   // pe = se[b] + lds_slot
      he[tid] = lofs;          // reuse as placement cursor
    }
  }
  __syncthreads();             // wtot reuse barrier
  // scan node hist (196 bins <= 256 threads)
  {
    int v = (tid < kNCN) ? hn[tid] : 0;
    int x = v;
#pragma unroll
    for (int d = 1; d < 64; d <<= 1) {
      int y = __shfl_up(x, d, 64);
      if (lane >= d) x += y;
    }
    if (lane == 63) wtot[wid] = x;
    __syncthreads();
    int add = 0;
    for (int w = 0; w < wid; ++w) add += wtot[w];
    if (tid < kNCN) {
      int lofs = x + add - v;
      int base = (v > 0) ? atomicAdd(&gcnt_n[tid], v) : 0;
      sn_[tid] = base - lofs;
      hn[tid] = lofs;
    }
  }
  __syncthreads();
  // pass 2: block-local counting-sort placement into LDS.
  // full pair packs in 32b: n < 2^17, h < 2^15.
  for (int i = s + tid; i < e; i += 256) {
    const unsigned n = (unsigned)node_idx[i];
    const unsigned h = (unsigned)hedge_idx[i];
    const int be = (int)(h >> 7);
    const int p = atomicAdd(&he[be], 1);
    lbuf_e[p] = (n << 15) | h;
    const int bn = (int)(n >> 9);
    const int q = atomicAdd(&hn[bn], 1);
    lbuf_n[q] = (h << 17) | n;
  }
  __syncthreads();
  // writeback: consecutive LDS slots within a bucket run -> consecutive global
  // addresses (coalesced, full lines, one XCD per run)
  for (int i = tid; i < cnt; i += 256) {
    const unsigned v = lbuf_e[i];
    const int h = (int)(v & 0x7FFFu);
    const int n = (int)(v >> 15);
    const int b = h >> 7;
    const int pe = se[b] + i;
    if (pe < kCapCE) buf_e[(long long)b * kCapCE + pe] = (n << 7) | (h & 127);
  }
  for (int i = tid; i < cnt; i += 256) {
    const unsigned v = lbuf_n[i];
    const int n = (int)(v & 0x1FFFFu);
    const int h = (int)(v >> 17);
    const int b = n >> 9;
    const int pn = sn_[b] + i;
    if (pn < kCapCN) buf_n[(long long)b * kCapCN + pn] = (h << 9) | (n & 511);
  }
}

// ---------- L2: sort each coarse bucket by low key bits, in place; emit segs ----------
// blocks [0,kNCE): edge buckets (128 bins); [kNCE, kNCE+kNCN): node buckets (512 bins).
__global__ __launch_bounds__(512) void subsort_kernel(
    int* __restrict__ buf_e, const int* __restrict__ gcnt_e, int* __restrict__ seg_e,
    int* __restrict__ buf_n, const int* __restrict__ gcnt_n, int* __restrict__ seg_n) {
  __shared__ int sbuf[kCapCE];       // 45 KB
  __shared__ int bins[513];
  __shared__ int cur[512];
  __shared__ int segs[513];
  __shared__ int wtot[8];
  const int tid = threadIdx.x;
  int nbins, shift, cnt; int* src; int* segout;
  if (blockIdx.x < kNCE) {
    int cb = blockIdx.x; nbins = 128; shift = 7;
    src = buf_e + (long long)cb * kCapCE;
    cnt = min(gcnt_e[cb], kCapCE);
    segout = seg_e + cb * 129;
  } else {
    int cb = blockIdx.x - kNCE; nbins = 512; shift = 9;
    src = buf_n + (long long)cb * kCapCN;
    cnt = min(gcnt_n[cb], kCapCN);
    segout = seg_n + cb * 513;
  }
  const int mask = nbins - 1;
  for (int i = tid; i < nbins; i += 512) bins[i] = 0;
  __syncthreads();
  for (int i = tid; i < cnt; i += 512) atomicAdd(&bins[src[i] & mask], 1);
  __syncthreads();
  // hierarchical exclusive scan of bins[0..nbins) (8 waves of 64)
  const int lane = tid & 63, wid = tid >> 6;
  int v = (tid < nbins) ? bins[tid] : 0;
  int x = v;
#pragma unroll
  for (int d = 1; d < 64; d <<= 1) {
    int y = __shfl_up(x, d, 64);
    if (lane >= d) x += y;
  }
  if (lane == 63) wtot[wid] = x;
  __syncthreads();
  int add = 0;
  for (int w = 0; w < wid; ++w) add += wtot[w];
  if (tid < nbins) { segs[tid + 1] = x + add; cur[tid] = x + add - v; }
  if (tid == 0) segs[0] = 0;
  __syncthreads();
  for (int i = tid; i < cnt; i += 512) {
    int p = src[i];
    int r = atomicAdd(&cur[p & mask], 1);
    sbuf[r] = p >> shift;              // payload only: sorted adjacency
  }
  __syncthreads();
  for (int i = tid; i < cnt; i += 512) src[i] = sbuf[i];   // coalesced writeback
  for (int j = tid; j <= nbins; j += 512) segout[j] = segs[j];
}

// ---------- gather features -> bf16 h_edge (mean), dim-sliced per XCD ----------
// slice = blockIdx % 8 == XCD id under round-robin dispatch. Each XCD only reads
// a 100000 x 32B slice of feat_bf (3.2 MB) -> L2-resident. Adjacency is streamed
// nontemporal so it doesn't evict the slice; h_edge stores are nontemporal.
__global__ __launch_bounds__(256) void gather_edge_v3(
    const unsigned* __restrict__ feat_bf, const int* __restrict__ buf_e,
    const int* __restrict__ seg_e, unsigned* __restrict__ h_edge, int n_hedges) {
  __shared__ int ebuf[kSliceE3];
  __shared__ int segl[33];
  const int bid = blockIdx.x;
  const int slice = bid & 7;          // == XCD under round-robin block dispatch
  const int hb = bid >> 3;
  const int tid = threadIdx.x;
  const int h0 = hb * 32;             // 32 hedges/block; 128%32==0 -> one bucket
  const int cb = h0 >> 7, j0 = h0 & 127;
  if (tid < 33) segl[tid] = seg_e[cb * 129 + j0 + tid];
  __syncthreads();
  const int sbase = segl[0];
  const int n_sl = min(segl[32] - sbase, kSliceE3);
  const int* src = buf_e + (long long)cb * kCapCE + sbase;
  for (int i = tid; i < n_sl; i += 256) ebuf[i] = __builtin_nontemporal_load(&src[i]);
  __syncthreads();
  const int g = tid >> 3, lane = tid & 7;   // 32 groups x 8 lanes
  const int gh = h0 + g;
  if (gh >= n_hedges) return;
  const int w = slice * 8 + lane;           // word (2 dims) this lane owns
  const unsigned* fw = feat_bf + w;
  const int deg = segl[g + 1] - segl[g];
  const int s0 = min(segl[g] - sbase, n_sl);
  const int e0 = min(segl[g + 1] - sbase, n_sl);
  float a0 = 0.f, a1 = 0.f, c0 = 0.f, c1 = 0.f;
  int j = s0;
  for (; j + 7 < e0; j += 8) {
    unsigned u0 = fw[(unsigned)ebuf[j] * 64u];
    unsigned u1 = fw[(unsigned)ebuf[j + 1] * 64u];
    unsigned u2 = fw[(unsigned)ebuf[j + 2] * 64u];
    unsigned u3 = fw[(unsigned)ebuf[j + 3] * 64u];
    unsigned u4 = fw[(unsigned)ebuf[j + 4] * 64u];
    unsigned u5 = fw[(unsigned)ebuf[j + 5] * 64u];
    unsigned u6 = fw[(unsigned)ebuf[j + 6] * 64u];
    unsigned u7 = fw[(unsigned)ebuf[j + 7] * 64u];
    a0 += u2f(u0 << 16); a1 += u2f(u0 & 0xFFFF0000u);
    c0 += u2f(u1 << 16); c1 += u2f(u1 & 0xFFFF0000u);
    a0 += u2f(u2 << 16); a1 += u2f(u2 & 0xFFFF0000u);
    c0 += u2f(u3 << 16); c1 += u2f(u3 & 0xFFFF0000u);
    a0 += u2f(u4 << 16); a1 += u2f(u4 & 0xFFFF0000u);
    c0 += u2f(u5 << 16); c1 += u2f(u5 & 0xFFFF0000u);
    a0 += u2f(u6 << 16); a1 += u2f(u6 & 0xFFFF0000u);
    c0 += u2f(u7 << 16); c1 += u2f(u7 & 0xFFFF0000u);
  }
  for (; j < e0; ++j) {
    unsigned u = fw[(unsigned)ebuf[j] * 64u];
    a0 += u2f(u << 16); a1 += u2f(u & 0xFFFF0000u);
  }
  a0 += c0; a1 += c1;
  const float inv = 1.0f / fmaxf((float)deg, 1.0f);
  __builtin_nontemporal_store(bfpack(a0 * inv, a1 * inv),
                              &h_edge[(unsigned)gh * 64u + w]);
}

// ---------- t_edge = h_edge @ W.T in place (bf16 io+W, fp32 acc) ----------
static constexpr int kWRow = 68;
__global__ __launch_bounds__(256) void edge_linear_v4(
    unsigned* __restrict__ h_edge, const float* __restrict__ W, int n_rows) {
  __shared__ unsigned Wt2[kD * kWRow];   // 34.8 KB: word j of row k = W^T[k][2j..2j+1]
  __shared__ float hT[kD * 64];          // 32 KB: hT[k][r]
  const int tid = threadIdx.x;
  const int row0 = blockIdx.x * 64;
  for (int i = tid; i < kD * 64; i += 256) {
    int k = i & 127, j = i >> 7;
    float c0 = W[(2 * j) * kD + k];
    float c1 = W[(2 * j + 1) * kD + k];
    Wt2[k * kWRow + j] = bfpack(c0, c1);
  }
  {
    const int r = tid & 63, o = tid >> 6;
    const uint4* hp = (const uint4*)(h_edge + (long long)(row0 + r) * 64 + o * 16);
#pragma unroll
    for (int q = 0; q < 4; ++q) {
      uint4 v = hp[q];
      int k0 = o * 32 + q * 8;
      hT[(k0 + 0) * 64 + r] = u2f(v.x << 16);
      hT[(k0 + 1) * 64 + r] = u2f(v.x & 0xFFFF0000u);
      hT[(k0 + 2) * 64 + r] = u2f(v.y << 16);
      hT[(k0 + 3) * 64 + r] = u2f(v.y & 0xFFFF0000u);
      hT[(k0 + 4) * 64 + r] = u2f(v.z << 16);
      hT[(k0 + 5) * 64 + r] = u2f(v.z & 0xFFFF0000u);
      hT[(k0 + 6) * 64 + r] = u2f(v.w << 16);
      hT[(k0 + 7) * 64 + r] = u2f(v.w & 0xFFFF0000u);
    }
  }
  __syncthreads();
  const int c8 = tid & 15;
  const int rg = tid >> 4;
  float4 acc[4][2] = {};
#pragma unroll 2
  for (int k = 0; k < kD; ++k) {
    const uint4 wp = *(const uint4*)(&Wt2[k * kWRow + c8 * 4]);
    const float4 h4 = *(const float4*)(&hT[k * 64 + rg * 4]);
    const float w0 = u2f(wp.x << 16), w1 = u2f(wp.x & 0xFFFF0000u);
    const float w2 = u2f(wp.y << 16), w3 = u2f(wp.y & 0xFFFF0000u);
    const float w4 = u2f(wp.z << 16), w5 = u2f(wp.z & 0xFFFF0000u);
    const float w6 = u2f(wp.w << 16), w7 = u2f(wp.w & 0xFFFF0000u);
    const float hh[4] = {h4.x, h4.y, h4.z, h4.w};
#pragma unroll
    for (int i = 0; i < 4; ++i) {
      acc[i][0].x = fmaf(hh[i], w0, acc[i][0].x);
      acc[i][0].y = fmaf(hh[i], w1, acc[i][0].y);
      acc[i][0].z = fmaf(hh[i], w2, acc[i][0].z);
      acc[i][0].w = fmaf(hh[i], w3, acc[i][0].w);
      acc[i][1].x = fmaf(hh[i], w4, acc[i][1].x);
      acc[i][1].y = fmaf(hh[i], w5, acc[i][1].y);
      acc[i][1].z = fmaf(hh[i], w6, acc[i][1].z);
      acc[i][1].w = fmaf(hh[i], w7, acc[i][1].w);
    }
  }
  long long rr = row0 + rg * 4;
#pragma unroll
  for (int i = 0; i < 4; ++i) {
    uint4 o;
    o.x = bfpack(acc[i][0].x, acc[i][0].y);
    o.y = bfpack(acc[i][0].z, acc[i][0].w);
    o.z = bfpack(acc[i][1].x, acc[i][1].y);
    o.w = bfpack(acc[i][1].z, acc[i][1].w);
    *(uint4*)(h_edge + (rr + i) * 64 + c8 * 4) = o;
  }
}

// ---------- gather t_edge -> fp32 out (mean) + bias, dim-sliced per XCD ----------
// t_edge slice per XCD = 20032 x 32B = 0.64 MB -> trivially L2-resident.
__global__ __launch_bounds__(256) void gather_node_v3(
    const unsigned* __restrict__ t_edge, const int* __restrict__ buf_n,
    const int* __restrict__ seg_n, const float* __restrict__ bias,
    float* __restrict__ out, int n_nodes) {
  __shared__ int ebuf[kSliceN];
  __shared__ int segl[33];
  const int bid = blockIdx.x;
  const int slice = bid & 7;
  const int nb = bid >> 3;
  const int tid = threadIdx.x;
  const int n0 = nb * 32;             // 32 nodes/block; 512%32==0 -> one bucket
  const int cb = n0 >> 9, j0 = n0 & 511;
  if (tid < 33) segl[tid] = seg_n[cb * 513 + j0 + tid];
  __syncthreads();
  const int sbase = segl[0];
  const int n_sl = min(segl[32] - sbase, kSliceN);
  const int* src = buf_n + (long long)cb * kCapCN + sbase;
  for (int i = tid; i < n_sl; i += 256) ebuf[i] = __builtin_nontemporal_load(&src[i]);
  __syncthreads();
  const int g = tid >> 3, lane = tid & 7;   // 32 groups x 8 lanes
  const int gn = n0 + g;
  if (gn >= n_nodes) return;
  const int w = slice * 8 + lane;
  const unsigned* tw = t_edge + w;
  const float2 bb = *(const float2*)(bias + 2 * w);
  const int deg = segl[g + 1] - segl[g];
  const int s0 = min(segl[g] - sbase, n_sl);
  const int e0 = min(segl[g + 1] - sbase, n_sl);
  float a0 = 0.f, a1 = 0.f, c0 = 0.f, c1 = 0.f;
  int j = s0;
  for (; j + 3 < e0; j += 4) {
    unsigned u0 = tw[(unsigned)ebuf[j] * 64u];
    unsigned u1 = tw[(unsigned)ebuf[j + 1] * 64u];
    unsigned u2 = tw[(unsigned)ebuf[j + 2] * 64u];
    unsigned u3 = tw[(unsigned)ebuf[j + 3] * 64u];
    a0 += u2f(u0 << 16); a1 += u2f(u0 & 0xFFFF0000u);
    c0 += u2f(u1 << 16); c1 += u2f(u1 & 0xFFFF0000u);
    a0 += u2f(u2 << 16); a1 += u2f(u2 & 0xFFFF0000u);
    c0 += u2f(u3 << 16); c1 += u2f(u3 & 0xFFFF0000u);
  }
  for (; j < e0; ++j) {
    unsigned u = tw[(unsigned)ebuf[j] * 64u];
    a0 += u2f(u << 16); a1 += u2f(u & 0xFFFF0000u);
  }
  a0 += c0; a1 += c1;
  const float inv = 1.0f / fmaxf((float)deg, 1.0f);
  float2 o;
  o.x = fmaf(a0, inv, bb.x);
  o.y = fmaf(a1, inv, bb.y);
  *(float2*)(out + (long long)gn * kD + 2 * w) = o;
}

extern "C" void kernel_launch(void* const* d_in, const int* in_sizes, int n_in,
                              void* d_out, int out_size, void* d_ws, size_t ws_size,
                              hipStream_t stream) {
  const float* feat      = (const float*)d_in[0];
  const float* W         = (const float*)d_in[1];
  const float* b         = (const float*)d_in[2];
  const int*   node_idx  = (const int*)d_in[3];
  const int*   hedge_idx = (const int*)d_in[4];

  const int n_pairs  = in_sizes[3];
  const int n_nodes  = in_sizes[0] / kD;
  const int n_hedges = kHedges;
  const int n_feat   = in_sizes[0];

  // feat_bf lives in d_out's buffer (25.6 of 51.2 MB; dead until final kernel)
  unsigned* feat_bf = (unsigned*)d_out;

  // Workspace (~20 MB)
  const int n_rows_pad = ((n_hedges + 63) / 64) * 64;          // 20032
  unsigned* h_edge = (unsigned*)d_ws;                          // 20032*64 words
  int* buf_e = (int*)(h_edge + (size_t)n_rows_pad * 64);       // kNCE*kCapCE
  int* buf_n = buf_e + (size_t)kNCE * kCapCE;                  // kNCN*kCapCN
  int* seg_e = buf_n + (size_t)kNCN * kCapCN;                  // kNCE*129
  int* seg_n = seg_e + (size_t)kNCE * 129;                     // kNCN*513
  int* gcnt_e = seg_n + (size_t)kNCN * 513;                    // kNCE
  int* gcnt_n = gcnt_e + kNCE;                                 // kNCN

  hipMemsetAsync(gcnt_e, 0, (size_t)(kNCE + kNCN) * sizeof(int), stream);

  // grid sized so per_block = ceil(n_pairs/grid) <= kPmax (LDS staging cap)
  int pgrid = (n_pairs + kPmax - 1) / kPmax;
  if (pgrid < 512) pgrid = 512;

  partition_coarse<<<pgrid, 256, 0, stream>>>(
      feat, feat_bf, n_feat,
      node_idx, hedge_idx, n_pairs, gcnt_e, buf_e, gcnt_n, buf_n);

  subsort_kernel<<<kNCE + kNCN, 512, 0, stream>>>(
      buf_e, gcnt_e, seg_e, buf_n, gcnt_n, seg_n);

  // 8 dim-slices x hedge-blocks; slice == bid%8 == XCD (round-robin dispatch)
  gather_edge_v3<<<8 * ((n_hedges + 31) / 32), 256, 0, stream>>>(
      feat_bf, buf_e, seg_e, h_edge, n_hedges);

  edge_linear_v4<<<n_rows_pad / 64, 256, 0, stream>>>(h_edge, W, n_rows_pad);

  gather_node_v3<<<8 * ((n_nodes + 31) / 32), 256, 0, stream>>>(
      h_edge, buf_n, seg_n, b, (float*)d_out, n_nodes);
}

// Round 4
// 287.034 us; speedup vs baseline: 1.5465x; 1.5465x over previous
//
#include <hip/hip_runtime.h>

static constexpr int kD = 128;
static constexpr int kHedges = 20000;

// Coarse partition: edge by h>>6 (64 hedges/bucket), node by n>>8 (256 nodes/bucket)
static constexpr int kNCE = 313;      // ceil(20000/64)
static constexpr int kCapCE = 5632;   // mean 5120 + ~7 sigma
static constexpr int kNCN = 391;      // ceil(100000/256)
static constexpr int kCapCN = 4608;   // mean 4096 + ~8 sigma
// gather slice caps
static constexpr int kSliceE = 896;   // 8 hedges/block: mean 640 + 10 sigma
static constexpr int kSliceN = 768;   // 32 nodes/block: mean 512 + 11 sigma
// partition block-local staging capacity (per_block = ceil(n_pairs/grid) must be <= this)
static constexpr int kPmax = 3200;

__device__ __forceinline__ float u2f(unsigned u) { return __uint_as_float(u); }
__device__ __forceinline__ unsigned f2u(float f) { return __float_as_uint(f); }

// round-to-nearest-even fp32 -> bf16, pack two into one uint
__device__ __forceinline__ unsigned bfpack(float x, float y) {
  unsigned ux = f2u(x); ux = (ux + 0x7FFFu + ((ux >> 16) & 1u)) >> 16;
  unsigned uy = f2u(y); uy = (uy + 0x7FFFu + ((uy >> 16) & 1u)) & 0xFFFF0000u;
  return ux | uy;
}
// accumulate 8 bf16 (uint4) into a[0..7]
__device__ __forceinline__ void bf8_acc(uint4 v, float* a) {
  a[0] += u2f(v.x << 16); a[1] += u2f(v.x & 0xFFFF0000u);
  a[2] += u2f(v.y << 16); a[3] += u2f(v.y & 0xFFFF0000u);
  a[4] += u2f(v.z << 16); a[5] += u2f(v.z & 0xFFFF0000u);
  a[6] += u2f(v.w << 16); a[7] += u2f(v.w & 0xFFFF0000u);
}

// ---------- L1: convert feats (fused) + partition pairs into coarse buckets ----------
// block-local counting-sort placement in LDS, then coalesced per-bucket run
// writeback (full-line stores from a single XCD) instead of per-pair 4B scatter.
__global__ __launch_bounds__(256) void partition_coarse(
    const float* __restrict__ feat, unsigned* __restrict__ feat_bf, int n_feat,
    const int* __restrict__ node_idx, const int* __restrict__ hedge_idx,
    int n_pairs,
    int* __restrict__ gcnt_e, int* __restrict__ buf_e,
    int* __restrict__ gcnt_n, int* __restrict__ buf_n) {
  __shared__ unsigned lbuf_e[kPmax];          // 12.8 KB
  __shared__ unsigned lbuf_n[kPmax];          // 12.8 KB
  __shared__ int he[kNCE], se[kNCE];          // cur counter / global shift (edge)
  __shared__ int hn[kNCN], sn_[kNCN];         // cur counter / global shift (node)
  __shared__ int wtot[4];
  const int tid = threadIdx.x;
  // fused feature conversion (grid-stride over uint4 groups of 8 floats)
  {
    const int n8 = n_feat >> 3;
    for (int t = blockIdx.x * 256 + tid; t < n8; t += gridDim.x * 256) {
      long long i = (long long)t * 8;
      const float4 v0 = *(const float4*)(feat + i);
      const float4 v1 = *(const float4*)(feat + i + 4);
      uint4 o;
      o.x = bfpack(v0.x, v0.y); o.y = bfpack(v0.z, v0.w);
      o.z = bfpack(v1.x, v1.y); o.w = bfpack(v1.z, v1.w);
      *(uint4*)(feat_bf + (i >> 1)) = o;
    }
  }
  const int per_block = (n_pairs + gridDim.x - 1) / gridDim.x;
  const int s = blockIdx.x * per_block;
  const int e = min(s + per_block, n_pairs);
  const int cnt = max(e - s, 0);              // <= kPmax by grid sizing
  for (int i = tid; i < kNCE; i += 256) he[i] = 0;
  for (int i = tid; i < kNCN; i += 256) hn[i] = 0;
  __syncthreads();
  // pass 1: local histograms for both keyings
  for (int i = s + tid; i < e; i += 256) {
    atomicAdd(&he[hedge_idx[i] >> 6], 1);
    atomicAdd(&hn[node_idx[i] >> 8], 1);
  }
  __syncthreads();
  const int lane = tid & 63, wid = tid >> 6;
  // scan edge hist (313 bins, 2 bins/thread): lofs = local exclusive prefix
  {
    const int b0i = 2 * tid, b1i = 2 * tid + 1;
    int b0 = (b0i < kNCE) ? he[b0i] : 0;
    int b1 = (b1i < kNCE) ? he[b1i] : 0;
    int v = b0 + b1;
    int x = v;
#pragma unroll
    for (int d = 1; d < 64; d <<= 1) {
      int y = __shfl_up(x, d, 64);
      if (lane >= d) x += y;
    }
    if (lane == 63) wtot[wid] = x;
    __syncthreads();
    int add = 0;
    for (int w = 0; w < wid; ++w) add += wtot[w];
    int excl = x + add - v;
    if (b0i < kNCE) {
      int base = (b0 > 0) ? atomicAdd(&gcnt_e[b0i], b0) : 0;
      se[b0i] = base - excl;   // pe = se[b] + lds_slot
      he[b0i] = excl;          // placement cursor
    }
    if (b1i < kNCE) {
      int base = (b1 > 0) ? atomicAdd(&gcnt_e[b1i], b1) : 0;
      se[b1i] = base - (excl + b0);
      he[b1i] = excl + b0;
    }
  }
  __syncthreads();             // wtot reuse barrier
  // scan node hist (391 bins, 2 bins/thread)
  {
    const int b0i = 2 * tid, b1i = 2 * tid + 1;
    int b0 = (b0i < kNCN) ? hn[b0i] : 0;
    int b1 = (b1i < kNCN) ? hn[b1i] : 0;
    int v = b0 + b1;
    int x = v;
#pragma unroll
    for (int d = 1; d < 64; d <<= 1) {
      int y = __shfl_up(x, d, 64);
      if (lane >= d) x += y;
    }
    if (lane == 63) wtot[wid] = x;
    __syncthreads();
    int add = 0;
    for (int w = 0; w < wid; ++w) add += wtot[w];
    int excl = x + add - v;
    if (b0i < kNCN) {
      int base = (b0 > 0) ? atomicAdd(&gcnt_n[b0i], b0) : 0;
      sn_[b0i] = base - excl;
      hn[b0i] = excl;
    }
    if (b1i < kNCN) {
      int base = (b1 > 0) ? atomicAdd(&gcnt_n[b1i], b1) : 0;
      sn_[b1i] = base - (excl + b0);
      hn[b1i] = excl + b0;
    }
  }
  __syncthreads();
  // pass 2: block-local counting-sort placement into LDS.
  // full pair packs in 32b: n < 2^17, h < 2^15.
  for (int i = s + tid; i < e; i += 256) {
    const unsigned n = (unsigned)node_idx[i];
    const unsigned h = (unsigned)hedge_idx[i];
    const int be = (int)(h >> 6);
    const int p = atomicAdd(&he[be], 1);
    lbuf_e[p] = (n << 15) | h;
    const int bn = (int)(n >> 8);
    const int q = atomicAdd(&hn[bn], 1);
    lbuf_n[q] = (h << 17) | n;
  }
  __syncthreads();
  // writeback: consecutive LDS slots within a bucket run -> consecutive global
  // addresses (coalesced full-line stores from a single XCD)
  for (int i = tid; i < cnt; i += 256) {
    const unsigned v = lbuf_e[i];
    const int h = (int)(v & 0x7FFFu);
    const int n = (int)(v >> 15);
    const int b = h >> 6;
    const int pe = se[b] + i;
    if (pe < kCapCE) buf_e[(long long)b * kCapCE + pe] = (n << 6) | (h & 63);
  }
  for (int i = tid; i < cnt; i += 256) {
    const unsigned v = lbuf_n[i];
    const int n = (int)(v & 0x1FFFFu);
    const int h = (int)(v >> 17);
    const int b = n >> 8;
    const int pn = sn_[b] + i;
    if (pn < kCapCN) buf_n[(long long)b * kCapCN + pn] = (h << 8) | (n & 255);
  }
}

// ---------- L2: sort each coarse bucket by low key bits, in place; emit segs ----------
// blocks [0,kNCE): edge buckets (64 bins); [kNCE, kNCE+kNCN): node buckets (256 bins).
__global__ __launch_bounds__(512) void subsort_kernel(
    int* __restrict__ buf_e, const int* __restrict__ gcnt_e, int* __restrict__ seg_e,
    int* __restrict__ buf_n, const int* __restrict__ gcnt_n, int* __restrict__ seg_n) {
  __shared__ int sbuf[kCapCE];       // 22.5 KB
  __shared__ int bins[257];
  __shared__ int cur[256];
  __shared__ int segs[257];
  __shared__ int wtot[8];
  const int tid = threadIdx.x;
  int nbins, shift, cnt; int* src; int* segout;
  if (blockIdx.x < kNCE) {
    int cb = blockIdx.x; nbins = 64; shift = 6;
    src = buf_e + (long long)cb * kCapCE;
    cnt = min(gcnt_e[cb], kCapCE);
    segout = seg_e + cb * 65;
  } else {
    int cb = blockIdx.x - kNCE; nbins = 256; shift = 8;
    src = buf_n + (long long)cb * kCapCN;
    cnt = min(gcnt_n[cb], kCapCN);
    segout = seg_n + cb * 257;
  }
  const int mask = nbins - 1;
  for (int i = tid; i < nbins; i += 512) bins[i] = 0;
  __syncthreads();
  for (int i = tid; i < cnt; i += 512) atomicAdd(&bins[src[i] & mask], 1);
  __syncthreads();
  // hierarchical exclusive scan of bins[0..nbins) (8 waves of 64)
  const int lane = tid & 63, wid = tid >> 6;
  int v = (tid < nbins) ? bins[tid] : 0;
  int x = v;
#pragma unroll
  for (int d = 1; d < 64; d <<= 1) {
    int y = __shfl_up(x, d, 64);
    if (lane >= d) x += y;
  }
  if (lane == 63) wtot[wid] = x;
  __syncthreads();
  int add = 0;
  for (int w = 0; w < wid; ++w) add += wtot[w];
  if (tid < nbins) { segs[tid + 1] = x + add; cur[tid] = x + add - v; }
  if (tid == 0) segs[0] = 0;
  __syncthreads();
  for (int i = tid; i < cnt; i += 512) {
    int p = src[i];
    int r = atomicAdd(&cur[p & mask], 1);
    sbuf[r] = p >> shift;              // payload only: sorted adjacency
  }
  __syncthreads();
  for (int i = tid; i < cnt; i += 512) src[i] = sbuf[i];   // coalesced writeback
  for (int j = tid; j <= nbins; j += 512) segout[j] = segs[j];
}

// ---------- gather features -> bf16 h_edge (mean) ----------
__global__ __launch_bounds__(128) void gather_edge_v2(
    const unsigned* __restrict__ feat_bf, const int* __restrict__ buf_e,
    const int* __restrict__ seg_e, unsigned* __restrict__ h_edge, int n_hedges) {
  __shared__ int ebuf[kSliceE];
  __shared__ int segl[9];
  const int b = blockIdx.x;            // 8 hedges per block
  const int tid = threadIdx.x;
  const int h0 = b * 8;
  const int cb = h0 >> 6, j0 = h0 & 63;
  if (tid < 9) segl[tid] = seg_e[cb * 65 + j0 + tid];
  __syncthreads();
  const int sbase = segl[0];
  const int n_sl = min(segl[8] - sbase, kSliceE);
  const int* src = buf_e + (long long)cb * kCapCE + sbase;
  for (int i = tid; i < n_sl; i += 128) ebuf[i] = src[i];
  __syncthreads();
  const int g = tid >> 4, lane = tid & 15, cw = lane * 4;
  int gh = h0 + g;
  if (gh >= n_hedges) return;
  const int deg = segl[g + 1] - segl[g];
  const int s0 = min(segl[g] - sbase, n_sl);
  const int e0 = min(segl[g + 1] - sbase, n_sl);
  float a[8] = {}, a2[8] = {};
  int j = s0;
  for (; j + 7 < e0; j += 8) {
    uint4 v0 = *(const uint4*)(feat_bf + (long long)ebuf[j] * 64 + cw);
    uint4 v1 = *(const uint4*)(feat_bf + (long long)ebuf[j + 1] * 64 + cw);
    uint4 v2 = *(const uint4*)(feat_bf + (long long)ebuf[j + 2] * 64 + cw);
    uint4 v3 = *(const uint4*)(feat_bf + (long long)ebuf[j + 3] * 64 + cw);
    uint4 v4 = *(const uint4*)(feat_bf + (long long)ebuf[j + 4] * 64 + cw);
    uint4 v5 = *(const uint4*)(feat_bf + (long long)ebuf[j + 5] * 64 + cw);
    uint4 v6 = *(const uint4*)(feat_bf + (long long)ebuf[j + 6] * 64 + cw);
    uint4 v7 = *(const uint4*)(feat_bf + (long long)ebuf[j + 7] * 64 + cw);
    bf8_acc(v0, a); bf8_acc(v1, a2); bf8_acc(v2, a); bf8_acc(v3, a2);
    bf8_acc(v4, a); bf8_acc(v5, a2); bf8_acc(v6, a); bf8_acc(v7, a2);
  }
  for (; j < e0; ++j) {
    uint4 v = *(const uint4*)(feat_bf + (long long)ebuf[j] * 64 + cw);
    bf8_acc(v, a);
  }
#pragma unroll
  for (int t = 0; t < 8; ++t) a[t] += a2[t];
  float inv = 1.0f / fmaxf((float)deg, 1.0f);
  uint4 o;
  o.x = bfpack(a[0] * inv, a[1] * inv);
  o.y = bfpack(a[2] * inv, a[3] * inv);
  o.z = bfpack(a[4] * inv, a[5] * inv);
  o.w = bfpack(a[6] * inv, a[7] * inv);
  *(uint4*)(h_edge + (long long)gh * 64 + cw) = o;
}

// ---------- t_edge = h_edge @ W.T in place (bf16 io+W, fp32 acc) ----------
static constexpr int kWRow = 68;
__global__ __launch_bounds__(256) void edge_linear_v4(
    unsigned* __restrict__ h_edge, const float* __restrict__ W, int n_rows) {
  __shared__ unsigned Wt2[kD * kWRow];   // 34.8 KB: word j of row k = W^T[k][2j..2j+1]
  __shared__ float hT[kD * 64];          // 32 KB: hT[k][r]
  const int tid = threadIdx.x;
  const int row0 = blockIdx.x * 64;
  for (int i = tid; i < kD * 64; i += 256) {
    int k = i & 127, j = i >> 7;
    float c0 = W[(2 * j) * kD + k];
    float c1 = W[(2 * j + 1) * kD + k];
    Wt2[k * kWRow + j] = bfpack(c0, c1);
  }
  {
    const int r = tid & 63, o = tid >> 6;
    const uint4* hp = (const uint4*)(h_edge + (long long)(row0 + r) * 64 + o * 16);
#pragma unroll
    for (int q = 0; q < 4; ++q) {
      uint4 v = hp[q];
      int k0 = o * 32 + q * 8;
      hT[(k0 + 0) * 64 + r] = u2f(v.x << 16);
      hT[(k0 + 1) * 64 + r] = u2f(v.x & 0xFFFF0000u);
      hT[(k0 + 2) * 64 + r] = u2f(v.y << 16);
      hT[(k0 + 3) * 64 + r] = u2f(v.y & 0xFFFF0000u);
      hT[(k0 + 4) * 64 + r] = u2f(v.z << 16);
      hT[(k0 + 5) * 64 + r] = u2f(v.z & 0xFFFF0000u);
      hT[(k0 + 6) * 64 + r] = u2f(v.w << 16);
      hT[(k0 + 7) * 64 + r] = u2f(v.w & 0xFFFF0000u);
    }
  }
  __syncthreads();
  const int c8 = tid & 15;
  const int rg = tid >> 4;
  float4 acc[4][2] = {};
#pragma unroll 2
  for (int k = 0; k < kD; ++k) {
    const uint4 wp = *(const uint4*)(&Wt2[k * kWRow + c8 * 4]);
    const float4 h4 = *(const float4*)(&hT[k * 64 + rg * 4]);
    const float w0 = u2f(wp.x << 16), w1 = u2f(wp.x & 0xFFFF0000u);
    const float w2 = u2f(wp.y << 16), w3 = u2f(wp.y & 0xFFFF0000u);
    const float w4 = u2f(wp.z << 16), w5 = u2f(wp.z & 0xFFFF0000u);
    const float w6 = u2f(wp.w << 16), w7 = u2f(wp.w & 0xFFFF0000u);
    const float hh[4] = {h4.x, h4.y, h4.z, h4.w};
#pragma unroll
    for (int i = 0; i < 4; ++i) {
      acc[i][0].x = fmaf(hh[i], w0, acc[i][0].x);
      acc[i][0].y = fmaf(hh[i], w1, acc[i][0].y);
      acc[i][0].z = fmaf(hh[i], w2, acc[i][0].z);
      acc[i][0].w = fmaf(hh[i], w3, acc[i][0].w);
      acc[i][1].x = fmaf(hh[i], w4, acc[i][1].x);
      acc[i][1].y = fmaf(hh[i], w5, acc[i][1].y);
      acc[i][1].z = fmaf(hh[i], w6, acc[i][1].z);
      acc[i][1].w = fmaf(hh[i], w7, acc[i][1].w);
    }
  }
  long long rr = row0 + rg * 4;
#pragma unroll
  for (int i = 0; i < 4; ++i) {
    uint4 o;
    o.x = bfpack(acc[i][0].x, acc[i][0].y);
    o.y = bfpack(acc[i][0].z, acc[i][0].w);
    o.z = bfpack(acc[i][1].x, acc[i][1].y);
    o.w = bfpack(acc[i][1].z, acc[i][1].w);
    *(uint4*)(h_edge + (rr + i) * 64 + c8 * 4) = o;
  }
}

// ---------- gather t_edge -> fp32 out (mean) + bias ----------
__global__ __launch_bounds__(128) void gather_node_v2(
    const unsigned* __restrict__ t_edge, const int* __restrict__ buf_n,
    const int* __restrict__ seg_n, const float* __restrict__ bias,
    float* __restrict__ out, int n_nodes) {
  __shared__ int ebuf[kSliceN];
  __shared__ int segl[33];
  const int b = blockIdx.x;            // 32 nodes per block
  const int tid = threadIdx.x;
  const int n0 = b * 32;
  const int cb = n0 >> 8, j0 = n0 & 255;
  if (tid < 33) segl[tid] = seg_n[cb * 257 + j0 + tid];
  __syncthreads();
  const int sbase = segl[0];
  const int n_sl = min(segl[32] - sbase, kSliceN);
  const int* src = buf_n + (long long)cb * kCapCN + sbase;
  for (int i = tid; i < n_sl; i += 128) ebuf[i] = src[i];
  __syncthreads();
  const int g = tid >> 4, lane = tid & 15, cw = lane * 4;
  const float4 b0 = *(const float4*)(bias + lane * 8);
  const float4 b1 = *(const float4*)(bias + lane * 8 + 4);
  for (int nl = g; nl < 32; nl += 8) {
    int gn = n0 + nl;
    if (gn >= n_nodes) continue;
    const int deg = segl[nl + 1] - segl[nl];
    const int s0 = min(segl[nl] - sbase, n_sl);
    const int e0 = min(segl[nl + 1] - sbase, n_sl);
    float a[8] = {}, a2[8] = {};
    int j = s0;
    for (; j + 7 < e0; j += 8) {
      uint4 v0 = *(const uint4*)(t_edge + (long long)ebuf[j] * 64 + cw);
      uint4 v1 = *(const uint4*)(t_edge + (long long)ebuf[j + 1] * 64 + cw);
      uint4 v2 = *(const uint4*)(t_edge + (long long)ebuf[j + 2] * 64 + cw);
      uint4 v3 = *(const uint4*)(t_edge + (long long)ebuf[j + 3] * 64 + cw);
      uint4 v4 = *(const uint4*)(t_edge + (long long)ebuf[j + 4] * 64 + cw);
      uint4 v5 = *(const uint4*)(t_edge + (long long)ebuf[j + 5] * 64 + cw);
      uint4 v6 = *(const uint4*)(t_edge + (long long)ebuf[j + 6] * 64 + cw);
      uint4 v7 = *(const uint4*)(t_edge + (long long)ebuf[j + 7] * 64 + cw);
      bf8_acc(v0, a); bf8_acc(v1, a2); bf8_acc(v2, a); bf8_acc(v3, a2);
      bf8_acc(v4, a); bf8_acc(v5, a2); bf8_acc(v6, a); bf8_acc(v7, a2);
    }
    for (; j < e0; ++j) {
      uint4 v = *(const uint4*)(t_edge + (long long)ebuf[j] * 64 + cw);
      bf8_acc(v, a);
    }
#pragma unroll
    for (int t = 0; t < 8; ++t) a[t] += a2[t];
    float inv = 1.0f / fmaxf((float)deg, 1.0f);
    float4 o0, o1;
    o0.x = fmaf(a[0], inv, b0.x); o0.y = fmaf(a[1], inv, b0.y);
    o0.z = fmaf(a[2], inv, b0.z); o0.w = fmaf(a[3], inv, b0.w);
    o1.x = fmaf(a[4], inv, b1.x); o1.y = fmaf(a[5], inv, b1.y);
    o1.z = fmaf(a[6], inv, b1.z); o1.w = fmaf(a[7], inv, b1.w);
    float* op = out + (long long)gn * kD + lane * 8;
    *(float4*)op = o0;
    *(float4*)(op + 4) = o1;
  }
}

extern "C" void kernel_launch(void* const* d_in, const int* in_sizes, int n_in,
                              void* d_out, int out_size, void* d_ws, size_t ws_size,
                              hipStream_t stream) {
  const float* feat      = (const float*)d_in[0];
  const float* W         = (const float*)d_in[1];
  const float* b         = (const float*)d_in[2];
  const int*   node_idx  = (const int*)d_in[3];
  const int*   hedge_idx = (const int*)d_in[4];

  const int n_pairs  = in_sizes[3];
  const int n_nodes  = in_sizes[0] / kD;
  const int n_hedges = kHedges;
  const int n_feat   = in_sizes[0];

  // feat_bf lives in d_out's buffer (25.6 of 51.2 MB; dead until final kernel)
  unsigned* feat_bf = (unsigned*)d_out;

  // Workspace (~19.9 MB)
  const int n_rows_pad = ((n_hedges + 63) / 64) * 64;          // 20032
  unsigned* h_edge = (unsigned*)d_ws;                          // 20032*64 words
  int* buf_e = (int*)(h_edge + (size_t)n_rows_pad * 64);       // kNCE*kCapCE
  int* buf_n = buf_e + (size_t)kNCE * kCapCE;                  // kNCN*kCapCN
  int* seg_e = buf_n + (size_t)kNCN * kCapCN;                  // kNCE*65
  int* seg_n = seg_e + (size_t)kNCE * 65;                      // kNCN*257
  int* gcnt_e = seg_n + (size_t)kNCN * 257;                    // kNCE
  int* gcnt_n = gcnt_e + kNCE;                                 // kNCN

  hipMemsetAsync(gcnt_e, 0, (size_t)(kNCE + kNCN) * sizeof(int), stream);

  // grid sized so per_block = ceil(n_pairs/grid) <= kPmax (LDS staging cap)
  int pgrid = (n_pairs + kPmax - 1) / kPmax;
  if (pgrid < 512) pgrid = 512;

  partition_coarse<<<pgrid, 256, 0, stream>>>(
      feat, feat_bf, n_feat,
      node_idx, hedge_idx, n_pairs, gcnt_e, buf_e, gcnt_n, buf_n);

  subsort_kernel<<<kNCE + kNCN, 512, 0, stream>>>(
      buf_e, gcnt_e, seg_e, buf_n, gcnt_n, seg_n);

  gather_edge_v2<<<(n_hedges + 7) / 8, 128, 0, stream>>>(
      feat_bf, buf_e, seg_e, h_edge, n_hedges);

  edge_linear_v4<<<n_rows_pad / 64, 256, 0, stream>>>(h_edge, W, n_rows_pad);

  gather_node_v2<<<(n_nodes + 31) / 32, 128, 0, stream>>>(
      h_edge, buf_n, seg_n, b, (float*)d_out, n_nodes);
}

// Round 5
// 278.943 us; speedup vs baseline: 1.5913x; 1.0290x over previous
//
#include <hip/hip_runtime.h>

static constexpr int kD = 128;
static constexpr int kHedges = 20000;

// Coarse partition: edge by h>>7 (128 hedges/bucket), node by n>>9 (512 nodes/bucket)
static constexpr int kNCE = 157;      // ceil(20000/128)
static constexpr int kCapCE = 11264;  // mean 10240 + 10 sigma
static constexpr int kNCN = 196;      // ceil(100000/512)
static constexpr int kCapCN = 9216;   // mean 8192 + 11 sigma
// gather slice caps
static constexpr int kSliceE4 = 1664; // 16 hedges/block: mean 1280 + ~10.6 sigma
static constexpr int kSliceN4 = 1408; // 64 nodes/block: mean 1024 + ~12 sigma
// partition block-local staging capacity (per_block = ceil(n_pairs/grid) must be <= this)
static constexpr int kPmax = 3200;

__device__ __forceinline__ float u2f(unsigned u) { return __uint_as_float(u); }
__device__ __forceinline__ unsigned f2u(float f) { return __float_as_uint(f); }

// round-to-nearest-even fp32 -> bf16, pack two into one uint
__device__ __forceinline__ unsigned bfpack(float x, float y) {
  unsigned ux = f2u(x); ux = (ux + 0x7FFFu + ((ux >> 16) & 1u)) >> 16;
  unsigned uy = f2u(y); uy = (uy + 0x7FFFu + ((uy >> 16) & 1u)) & 0xFFFF0000u;
  return ux | uy;
}
// accumulate 8 bf16 (uint4) into a[0..7]
__device__ __forceinline__ void bf8_acc(uint4 v, float* a) {
  a[0] += u2f(v.x << 16); a[1] += u2f(v.x & 0xFFFF0000u);
  a[2] += u2f(v.y << 16); a[3] += u2f(v.y & 0xFFFF0000u);
  a[4] += u2f(v.z << 16); a[5] += u2f(v.z & 0xFFFF0000u);
  a[6] += u2f(v.w << 16); a[7] += u2f(v.w & 0xFFFF0000u);
}

// ---------- L1: convert feats (fused) + partition pairs into coarse buckets ----------
// block-local counting-sort placement in LDS, then coalesced per-bucket run
// writeback (full-line stores from a single XCD) instead of per-pair 4B scatter.
__global__ __launch_bounds__(256) void partition_coarse(
    const float* __restrict__ feat, unsigned* __restrict__ feat_bf, int n_feat,
    const int* __restrict__ node_idx, const int* __restrict__ hedge_idx,
    int n_pairs,
    int* __restrict__ gcnt_e, int* __restrict__ buf_e,
    int* __restrict__ gcnt_n, int* __restrict__ buf_n) {
  __shared__ unsigned lbuf_e[kPmax];          // 12.8 KB
  __shared__ unsigned lbuf_n[kPmax];          // 12.8 KB
  __shared__ int he[kNCE], se[kNCE];          // cur counter / global shift (edge)
  __shared__ int hn[kNCN], sn_[kNCN];         // cur counter / global shift (node)
  __shared__ int wtot[4];
  const int tid = threadIdx.x;
  // fused feature conversion (grid-stride over uint4 groups of 8 floats)
  {
    const int n8 = n_feat >> 3;
    for (int t = blockIdx.x * 256 + tid; t < n8; t += gridDim.x * 256) {
      long long i = (long long)t * 8;
      const float4 v0 = *(const float4*)(feat + i);
      const float4 v1 = *(const float4*)(feat + i + 4);
      uint4 o;
      o.x = bfpack(v0.x, v0.y); o.y = bfpack(v0.z, v0.w);
      o.z = bfpack(v1.x, v1.y); o.w = bfpack(v1.z, v1.w);
      *(uint4*)(feat_bf + (i >> 1)) = o;
    }
  }
  const int per_block = (n_pairs + gridDim.x - 1) / gridDim.x;
  const int s = blockIdx.x * per_block;
  const int e = min(s + per_block, n_pairs);
  const int cnt = max(e - s, 0);              // <= kPmax by grid sizing
  for (int i = tid; i < kNCE; i += 256) he[i] = 0;
  for (int i = tid; i < kNCN; i += 256) hn[i] = 0;
  __syncthreads();
  // pass 1: local histograms for both keyings
  for (int i = s + tid; i < e; i += 256) {
    atomicAdd(&he[hedge_idx[i] >> 7], 1);
    atomicAdd(&hn[node_idx[i] >> 9], 1);
  }
  __syncthreads();
  const int lane = tid & 63, wid = tid >> 6;
  // scan edge hist (157 bins <= 256 threads): lofs = local exclusive prefix
  {
    int v = (tid < kNCE) ? he[tid] : 0;
    int x = v;
#pragma unroll
    for (int d = 1; d < 64; d <<= 1) {
      int y = __shfl_up(x, d, 64);
      if (lane >= d) x += y;
    }
    if (lane == 63) wtot[wid] = x;
    __syncthreads();
    int add = 0;
    for (int w = 0; w < wid; ++w) add += wtot[w];
    if (tid < kNCE) {
      int lofs = x + add - v;
      int base = (v > 0) ? atomicAdd(&gcnt_e[tid], v) : 0;
      se[tid] = base - lofs;   // pe = se[b] + lds_slot
      he[tid] = lofs;          // reuse as placement cursor
    }
  }
  __syncthreads();             // wtot reuse barrier
  // scan node hist (196 bins <= 256 threads)
  {
    int v = (tid < kNCN) ? hn[tid] : 0;
    int x = v;
#pragma unroll
    for (int d = 1; d < 64; d <<= 1) {
      int y = __shfl_up(x, d, 64);
      if (lane >= d) x += y;
    }
    if (lane == 63) wtot[wid] = x;
    __syncthreads();
    int add = 0;
    for (int w = 0; w < wid; ++w) add += wtot[w];
    if (tid < kNCN) {
      int lofs = x + add - v;
      int base = (v > 0) ? atomicAdd(&gcnt_n[tid], v) : 0;
      sn_[tid] = base - lofs;
      hn[tid] = lofs;
    }
  }
  __syncthreads();
  // pass 2: block-local counting-sort placement into LDS.
  // full pair packs in 32b: n < 2^17, h < 2^15.
  for (int i = s + tid; i < e; i += 256) {
    const unsigned n = (unsigned)node_idx[i];
    const unsigned h = (unsigned)hedge_idx[i];
    const int be = (int)(h >> 7);
    const int p = atomicAdd(&he[be], 1);
    lbuf_e[p] = (n << 15) | h;
    const int bn = (int)(n >> 9);
    const int q = atomicAdd(&hn[bn], 1);
    lbuf_n[q] = (h << 17) | n;
  }
  __syncthreads();
  // writeback: consecutive LDS slots within a bucket run -> consecutive global
  // addresses (coalesced, full lines, one XCD per run)
  for (int i = tid; i < cnt; i += 256) {
    const unsigned v = lbuf_e[i];
    const int h = (int)(v & 0x7FFFu);
    const int n = (int)(v >> 15);
    const int b = h >> 7;
    const int pe = se[b] + i;
    if (pe < kCapCE) buf_e[(long long)b * kCapCE + pe] = (n << 7) | (h & 127);
  }
  for (int i = tid; i < cnt; i += 256) {
    const unsigned v = lbuf_n[i];
    const int n = (int)(v & 0x1FFFFu);
    const int h = (int)(v >> 17);
    const int b = n >> 9;
    const int pn = sn_[b] + i;
    if (pn < kCapCN) buf_n[(long long)b * kCapCN + pn] = (h << 9) | (n & 511);
  }
}

// ---------- L2: sort each coarse bucket by low key bits, in place; emit segs ----------
// blocks [0,kNCE): edge buckets (128 bins); [kNCE, kNCE+kNCN): node buckets (512 bins).
__global__ __launch_bounds__(512) void subsort_kernel(
    int* __restrict__ buf_e, const int* __restrict__ gcnt_e, int* __restrict__ seg_e,
    int* __restrict__ buf_n, const int* __restrict__ gcnt_n, int* __restrict__ seg_n) {
  __shared__ int sbuf[kCapCE];       // 45 KB
  __shared__ int bins[513];
  __shared__ int cur[512];
  __shared__ int segs[513];
  __shared__ int wtot[8];
  const int tid = threadIdx.x;
  int nbins, shift, cnt; int* src; int* segout;
  if (blockIdx.x < kNCE) {
    int cb = blockIdx.x; nbins = 128; shift = 7;
    src = buf_e + (long long)cb * kCapCE;
    cnt = min(gcnt_e[cb], kCapCE);
    segout = seg_e + cb * 129;
  } else {
    int cb = blockIdx.x - kNCE; nbins = 512; shift = 9;
    src = buf_n + (long long)cb * kCapCN;
    cnt = min(gcnt_n[cb], kCapCN);
    segout = seg_n + cb * 513;
  }
  const int mask = nbins - 1;
  for (int i = tid; i < nbins; i += 512) bins[i] = 0;
  __syncthreads();
  for (int i = tid; i < cnt; i += 512) atomicAdd(&bins[src[i] & mask], 1);
  __syncthreads();
  // hierarchical exclusive scan of bins[0..nbins) (8 waves of 64)
  const int lane = tid & 63, wid = tid >> 6;
  int v = (tid < nbins) ? bins[tid] : 0;
  int x = v;
#pragma unroll
  for (int d = 1; d < 64; d <<= 1) {
    int y = __shfl_up(x, d, 64);
    if (lane >= d) x += y;
  }
  if (lane == 63) wtot[wid] = x;
  __syncthreads();
  int add = 0;
  for (int w = 0; w < wid; ++w) add += wtot[w];
  if (tid < nbins) { segs[tid + 1] = x + add; cur[tid] = x + add - v; }
  if (tid == 0) segs[0] = 0;
  __syncthreads();
  for (int i = tid; i < cnt; i += 512) {
    int p = src[i];
    int r = atomicAdd(&cur[p & mask], 1);
    sbuf[r] = p >> shift;              // payload only: sorted adjacency
  }
  __syncthreads();
  for (int i = tid; i < cnt; i += 512) src[i] = sbuf[i];   // coalesced writeback
  for (int j = tid; j <= nbins; j += 512) segout[j] = segs[j];
}

// ---------- gather features -> bf16 h_edge (mean), MLP-pipelined ----------
// 256 thr / 16 hedges per block; inner loop software-pipelined: issue next
// 8 loads before accumulating current 8 -> loads continuously in flight.
__global__ __launch_bounds__(256) void gather_edge_v4(
    const unsigned* __restrict__ feat_bf, const int* __restrict__ buf_e,
    const int* __restrict__ seg_e, unsigned* __restrict__ h_edge, int n_hedges) {
  __shared__ int ebuf[kSliceE4];
  __shared__ int segl[17];
  const int b = blockIdx.x;            // 16 hedges per block
  const int tid = threadIdx.x;
  const int h0 = b * 16;
  const int cb = h0 >> 7, j0 = h0 & 127;
  if (tid < 17) segl[tid] = seg_e[cb * 129 + j0 + tid];
  __syncthreads();
  const int sbase = segl[0];
  const int n_sl = min(segl[16] - sbase, kSliceE4);
  const int* src = buf_e + (long long)cb * kCapCE + sbase;
  for (int i = tid; i < n_sl; i += 256) ebuf[i] = src[i];
  __syncthreads();
  const int g = tid >> 4, lane = tid & 15, cw = lane * 4;
  int gh = h0 + g;
  if (gh >= n_hedges) return;
  const int deg = segl[g + 1] - segl[g];
  const int s0 = min(segl[g] - sbase, n_sl);
  const int e0 = min(segl[g + 1] - sbase, n_sl);
  float a[8] = {}, a2[8] = {};
  int j = s0;
  const int jend8 = s0 + ((e0 - s0) & ~7);
  if (j < jend8) {
    // preload batch A
    uint4 A0 = *(const uint4*)(feat_bf + (long long)ebuf[j] * 64 + cw);
    uint4 A1 = *(const uint4*)(feat_bf + (long long)ebuf[j + 1] * 64 + cw);
    uint4 A2 = *(const uint4*)(feat_bf + (long long)ebuf[j + 2] * 64 + cw);
    uint4 A3 = *(const uint4*)(feat_bf + (long long)ebuf[j + 3] * 64 + cw);
    uint4 A4 = *(const uint4*)(feat_bf + (long long)ebuf[j + 4] * 64 + cw);
    uint4 A5 = *(const uint4*)(feat_bf + (long long)ebuf[j + 5] * 64 + cw);
    uint4 A6 = *(const uint4*)(feat_bf + (long long)ebuf[j + 6] * 64 + cw);
    uint4 A7 = *(const uint4*)(feat_bf + (long long)ebuf[j + 7] * 64 + cw);
    j += 8;
    for (; j < jend8; j += 8) {
      // issue batch B loads (fly while accumulating A)
      uint4 B0 = *(const uint4*)(feat_bf + (long long)ebuf[j] * 64 + cw);
      uint4 B1 = *(const uint4*)(feat_bf + (long long)ebuf[j + 1] * 64 + cw);
      uint4 B2 = *(const uint4*)(feat_bf + (long long)ebuf[j + 2] * 64 + cw);
      uint4 B3 = *(const uint4*)(feat_bf + (long long)ebuf[j + 3] * 64 + cw);
      uint4 B4 = *(const uint4*)(feat_bf + (long long)ebuf[j + 4] * 64 + cw);
      uint4 B5 = *(const uint4*)(feat_bf + (long long)ebuf[j + 5] * 64 + cw);
      uint4 B6 = *(const uint4*)(feat_bf + (long long)ebuf[j + 6] * 64 + cw);
      uint4 B7 = *(const uint4*)(feat_bf + (long long)ebuf[j + 7] * 64 + cw);
      bf8_acc(A0, a); bf8_acc(A1, a2); bf8_acc(A2, a); bf8_acc(A3, a2);
      bf8_acc(A4, a); bf8_acc(A5, a2); bf8_acc(A6, a); bf8_acc(A7, a2);
      A0 = B0; A1 = B1; A2 = B2; A3 = B3;
      A4 = B4; A5 = B5; A6 = B6; A7 = B7;
    }
    bf8_acc(A0, a); bf8_acc(A1, a2); bf8_acc(A2, a); bf8_acc(A3, a2);
    bf8_acc(A4, a); bf8_acc(A5, a2); bf8_acc(A6, a); bf8_acc(A7, a2);
  }
  for (; j < e0; ++j) {
    uint4 v = *(const uint4*)(feat_bf + (long long)ebuf[j] * 64 + cw);
    bf8_acc(v, a);
  }
#pragma unroll
  for (int t = 0; t < 8; ++t) a[t] += a2[t];
  float inv = 1.0f / fmaxf((float)deg, 1.0f);
  uint4 o;
  o.x = bfpack(a[0] * inv, a[1] * inv);
  o.y = bfpack(a[2] * inv, a[3] * inv);
  o.z = bfpack(a[4] * inv, a[5] * inv);
  o.w = bfpack(a[6] * inv, a[7] * inv);
  *(uint4*)(h_edge + (long long)gh * 64 + cw) = o;
}

// ---------- t_edge = h_edge @ W.T in place (bf16 io+W, fp32 acc) ----------
static constexpr int kWRow = 68;
__global__ __launch_bounds__(256) void edge_linear_v4(
    unsigned* __restrict__ h_edge, const float* __restrict__ W, int n_rows) {
  __shared__ unsigned Wt2[kD * kWRow];   // 34.8 KB: word j of row k = W^T[k][2j..2j+1]
  __shared__ float hT[kD * 64];          // 32 KB: hT[k][r]
  const int tid = threadIdx.x;
  const int row0 = blockIdx.x * 64;
  for (int i = tid; i < kD * 64; i += 256) {
    int k = i & 127, j = i >> 7;
    float c0 = W[(2 * j) * kD + k];
    float c1 = W[(2 * j + 1) * kD + k];
    Wt2[k * kWRow + j] = bfpack(c0, c1);
  }
  {
    const int r = tid & 63, o = tid >> 6;
    const uint4* hp = (const uint4*)(h_edge + (long long)(row0 + r) * 64 + o * 16);
#pragma unroll
    for (int q = 0; q < 4; ++q) {
      uint4 v = hp[q];
      int k0 = o * 32 + q * 8;
      hT[(k0 + 0) * 64 + r] = u2f(v.x << 16);
      hT[(k0 + 1) * 64 + r] = u2f(v.x & 0xFFFF0000u);
      hT[(k0 + 2) * 64 + r] = u2f(v.y << 16);
      hT[(k0 + 3) * 64 + r] = u2f(v.y & 0xFFFF0000u);
      hT[(k0 + 4) * 64 + r] = u2f(v.z << 16);
      hT[(k0 + 5) * 64 + r] = u2f(v.z & 0xFFFF0000u);
      hT[(k0 + 6) * 64 + r] = u2f(v.w << 16);
      hT[(k0 + 7) * 64 + r] = u2f(v.w & 0xFFFF0000u);
    }
  }
  __syncthreads();
  const int c8 = tid & 15;
  const int rg = tid >> 4;
  float4 acc[4][2] = {};
#pragma unroll 2
  for (int k = 0; k < kD; ++k) {
    const uint4 wp = *(const uint4*)(&Wt2[k * kWRow + c8 * 4]);
    const float4 h4 = *(const float4*)(&hT[k * 64 + rg * 4]);
    const float w0 = u2f(wp.x << 16), w1 = u2f(wp.x & 0xFFFF0000u);
    const float w2 = u2f(wp.y << 16), w3 = u2f(wp.y & 0xFFFF0000u);
    const float w4 = u2f(wp.z << 16), w5 = u2f(wp.z & 0xFFFF0000u);
    const float w6 = u2f(wp.w << 16), w7 = u2f(wp.w & 0xFFFF0000u);
    const float hh[4] = {h4.x, h4.y, h4.z, h4.w};
#pragma unroll
    for (int i = 0; i < 4; ++i) {
      acc[i][0].x = fmaf(hh[i], w0, acc[i][0].x);
      acc[i][0].y = fmaf(hh[i], w1, acc[i][0].y);
      acc[i][0].z = fmaf(hh[i], w2, acc[i][0].z);
      acc[i][0].w = fmaf(hh[i], w3, acc[i][0].w);
      acc[i][1].x = fmaf(hh[i], w4, acc[i][1].x);
      acc[i][1].y = fmaf(hh[i], w5, acc[i][1].y);
      acc[i][1].z = fmaf(hh[i], w6, acc[i][1].z);
      acc[i][1].w = fmaf(hh[i], w7, acc[i][1].w);
    }
  }
  long long rr = row0 + rg * 4;
#pragma unroll
  for (int i = 0; i < 4; ++i) {
    uint4 o;
    o.x = bfpack(acc[i][0].x, acc[i][0].y);
    o.y = bfpack(acc[i][0].z, acc[i][0].w);
    o.z = bfpack(acc[i][1].x, acc[i][1].y);
    o.w = bfpack(acc[i][1].z, acc[i][1].w);
    *(uint4*)(h_edge + (rr + i) * 64 + c8 * 4) = o;
  }
}

// ---------- gather t_edge -> fp32 out (mean) + bias, MLP-pipelined ----------
// 256 thr / 64 nodes per block (16 groups x 16 lanes, 4 nodes per group).
__global__ __launch_bounds__(256) void gather_node_v4(
    const unsigned* __restrict__ t_edge, const int* __restrict__ buf_n,
    const int* __restrict__ seg_n, const float* __restrict__ bias,
    float* __restrict__ out, int n_nodes) {
  __shared__ int ebuf[kSliceN4];
  __shared__ int segl[65];
  const int b = blockIdx.x;            // 64 nodes per block
  const int tid = threadIdx.x;
  const int n0 = b * 64;
  const int cb = n0 >> 9, j0 = n0 & 511;
  if (tid < 65) segl[tid] = seg_n[cb * 513 + j0 + tid];
  __syncthreads();
  const int sbase = segl[0];
  const int n_sl = min(segl[64] - sbase, kSliceN4);
  const int* src = buf_n + (long long)cb * kCapCN + sbase;
  for (int i = tid; i < n_sl; i += 256) ebuf[i] = src[i];
  __syncthreads();
  const int g = tid >> 4, lane = tid & 15, cw = lane * 4;
  const float4 b0 = *(const float4*)(bias + lane * 8);
  const float4 b1 = *(const float4*)(bias + lane * 8 + 4);
  for (int nl = g; nl < 64; nl += 16) {
    int gn = n0 + nl;
    if (gn >= n_nodes) continue;
    const int deg = segl[nl + 1] - segl[nl];
    const int s0 = min(segl[nl] - sbase, n_sl);
    const int e0 = min(segl[nl + 1] - sbase, n_sl);
    float a[8] = {}, a2[8] = {};
    int j = s0;
    const int jend8 = s0 + ((e0 - s0) & ~7);
    if (j < jend8) {
      uint4 A0 = *(const uint4*)(t_edge + (long long)ebuf[j] * 64 + cw);
      uint4 A1 = *(const uint4*)(t_edge + (long long)ebuf[j + 1] * 64 + cw);
      uint4 A2 = *(const uint4*)(t_edge + (long long)ebuf[j + 2] * 64 + cw);
      uint4 A3 = *(const uint4*)(t_edge + (long long)ebuf[j + 3] * 64 + cw);
      uint4 A4 = *(const uint4*)(t_edge + (long long)ebuf[j + 4] * 64 + cw);
      uint4 A5 = *(const uint4*)(t_edge + (long long)ebuf[j + 5] * 64 + cw);
      uint4 A6 = *(const uint4*)(t_edge + (long long)ebuf[j + 6] * 64 + cw);
      uint4 A7 = *(const uint4*)(t_edge + (long long)ebuf[j + 7] * 64 + cw);
      j += 8;
      for (; j < jend8; j += 8) {
        uint4 B0 = *(const uint4*)(t_edge + (long long)ebuf[j] * 64 + cw);
        uint4 B1 = *(const uint4*)(t_edge + (long long)ebuf[j + 1] * 64 + cw);
        uint4 B2 = *(const uint4*)(t_edge + (long long)ebuf[j + 2] * 64 + cw);
        uint4 B3 = *(const uint4*)(t_edge + (long long)ebuf[j + 3] * 64 + cw);
        uint4 B4 = *(const uint4*)(t_edge + (long long)ebuf[j + 4] * 64 + cw);
        uint4 B5 = *(const uint4*)(t_edge + (long long)ebuf[j + 5] * 64 + cw);
        uint4 B6 = *(const uint4*)(t_edge + (long long)ebuf[j + 6] * 64 + cw);
        uint4 B7 = *(const uint4*)(t_edge + (long long)ebuf[j + 7] * 64 + cw);
        bf8_acc(A0, a); bf8_acc(A1, a2); bf8_acc(A2, a); bf8_acc(A3, a2);
        bf8_acc(A4, a); bf8_acc(A5, a2); bf8_acc(A6, a); bf8_acc(A7, a2);
        A0 = B0; A1 = B1; A2 = B2; A3 = B3;
        A4 = B4; A5 = B5; A6 = B6; A7 = B7;
      }
      bf8_acc(A0, a); bf8_acc(A1, a2); bf8_acc(A2, a); bf8_acc(A3, a2);
      bf8_acc(A4, a); bf8_acc(A5, a2); bf8_acc(A6, a); bf8_acc(A7, a2);
    }
    for (; j < e0; ++j) {
      uint4 v = *(const uint4*)(t_edge + (long long)ebuf[j] * 64 + cw);
      bf8_acc(v, a);
    }
#pragma unroll
    for (int t = 0; t < 8; ++t) a[t] += a2[t];
    float inv = 1.0f / fmaxf((float)deg, 1.0f);
    float4 o0, o1;
    o0.x = fmaf(a[0], inv, b0.x); o0.y = fmaf(a[1], inv, b0.y);
    o0.z = fmaf(a[2], inv, b0.z); o0.w = fmaf(a[3], inv, b0.w);
    o1.x = fmaf(a[4], inv, b1.x); o1.y = fmaf(a[5], inv, b1.y);
    o1.z = fmaf(a[6], inv, b1.z); o1.w = fmaf(a[7], inv, b1.w);
    float* op = out + (long long)gn * kD + lane * 8;
    *(float4*)op = o0;
    *(float4*)(op + 4) = o1;
  }
}

extern "C" void kernel_launch(void* const* d_in, const int* in_sizes, int n_in,
                              void* d_out, int out_size, void* d_ws, size_t ws_size,
                              hipStream_t stream) {
  const float* feat      = (const float*)d_in[0];
  const float* W         = (const float*)d_in[1];
  const float* b         = (const float*)d_in[2];
  const int*   node_idx  = (const int*)d_in[3];
  const int*   hedge_idx = (const int*)d_in[4];

  const int n_pairs  = in_sizes[3];
  const int n_nodes  = in_sizes[0] / kD;
  const int n_hedges = kHedges;
  const int n_feat   = in_sizes[0];

  // feat_bf lives in d_out's buffer (25.6 of 51.2 MB; dead until final kernel)
  unsigned* feat_bf = (unsigned*)d_out;

  // Workspace (~20 MB)
  const int n_rows_pad = ((n_hedges + 63) / 64) * 64;          // 20032
  unsigned* h_edge = (unsigned*)d_ws;                          // 20032*64 words
  int* buf_e = (int*)(h_edge + (size_t)n_rows_pad * 64);       // kNCE*kCapCE
  int* buf_n = buf_e + (size_t)kNCE * kCapCE;                  // kNCN*kCapCN
  int* seg_e = buf_n + (size_t)kNCN * kCapCN;                  // kNCE*129
  int* seg_n = seg_e + (size_t)kNCE * 129;                     // kNCN*513
  int* gcnt_e = seg_n + (size_t)kNCN * 513;                    // kNCE
  int* gcnt_n = gcnt_e + kNCE;                                 // kNCN

  hipMemsetAsync(gcnt_e, 0, (size_t)(kNCE + kNCN) * sizeof(int), stream);

  // grid sized so per_block = ceil(n_pairs/grid) <= kPmax (LDS staging cap)
  int pgrid = (n_pairs + kPmax - 1) / kPmax;
  if (pgrid < 512) pgrid = 512;

  partition_coarse<<<pgrid, 256, 0, stream>>>(
      feat, feat_bf, n_feat,
      node_idx, hedge_idx, n_pairs, gcnt_e, buf_e, gcnt_n, buf_n);

  subsort_kernel<<<kNCE + kNCN, 512, 0, stream>>>(
      buf_e, gcnt_e, seg_e, buf_n, gcnt_n, seg_n);

  gather_edge_v4<<<(n_hedges + 15) / 16, 256, 0, stream>>>(
      feat_bf, buf_e, seg_e, h_edge, n_hedges);

  edge_linear_v4<<<n_rows_pad / 64, 256, 0, stream>>>(h_edge, W, n_rows_pad);

  gather_node_v4<<<(n_nodes + 63) / 64, 256, 0, stream>>>(
      h_edge, buf_n, seg_n, b, (float*)d_out, n_nodes);
}

// Round 6
// 276.495 us; speedup vs baseline: 1.6054x; 1.0089x over previous
//
#include <hip/hip_runtime.h>

static constexpr int kD = 128;
static constexpr int kHedges = 20000;

// Coarse partition: edge by h>>7 (128 hedges/bucket), node by n>>9 (512 nodes/bucket)
static constexpr int kNCE = 157;      // ceil(20000/128)
static constexpr int kCapCE = 11264;  // mean 10240 + 10 sigma
static constexpr int kNCN = 196;      // ceil(100000/512)
static constexpr int kCapCN = 9216;   // mean 8192 + 11 sigma
// gather slice caps
static constexpr int kSliceE4 = 1664; // 16 hedges/block: mean 1280 + ~10.6 sigma
static constexpr int kSliceN4 = 1408; // 64 nodes/block: mean 1024 + ~12 sigma
// partition block-local staging capacity (per_block = ceil(n_pairs/grid) must be <= this)
static constexpr int kPmax = 3200;
static constexpr int kWRow = 68;      // padded Wt2 row (words) to break bank strides

__device__ __forceinline__ float u2f(unsigned u) { return __uint_as_float(u); }
__device__ __forceinline__ unsigned f2u(float f) { return __float_as_uint(f); }

// round-to-nearest-even fp32 -> bf16, pack two into one uint
__device__ __forceinline__ unsigned bfpack(float x, float y) {
  unsigned ux = f2u(x); ux = (ux + 0x7FFFu + ((ux >> 16) & 1u)) >> 16;
  unsigned uy = f2u(y); uy = (uy + 0x7FFFu + ((uy >> 16) & 1u)) & 0xFFFF0000u;
  return ux | uy;
}
// accumulate 8 bf16 (uint4) into a[0..7]
__device__ __forceinline__ void bf8_acc(uint4 v, float* a) {
  a[0] += u2f(v.x << 16); a[1] += u2f(v.x & 0xFFFF0000u);
  a[2] += u2f(v.y << 16); a[3] += u2f(v.y & 0xFFFF0000u);
  a[4] += u2f(v.z << 16); a[5] += u2f(v.z & 0xFFFF0000u);
  a[6] += u2f(v.w << 16); a[7] += u2f(v.w & 0xFFFF0000u);
}

// ---------- L1: convert feats (fused) + partition pairs into coarse buckets ----------
// block-local counting-sort placement in LDS, then coalesced per-bucket run
// writeback (full-line stores from a single XCD) instead of per-pair 4B scatter.
__global__ __launch_bounds__(256) void partition_coarse(
    const float* __restrict__ feat, unsigned* __restrict__ feat_bf, int n_feat,
    const int* __restrict__ node_idx, const int* __restrict__ hedge_idx,
    int n_pairs,
    int* __restrict__ gcnt_e, int* __restrict__ buf_e,
    int* __restrict__ gcnt_n, int* __restrict__ buf_n) {
  __shared__ unsigned lbuf_e[kPmax];          // 12.8 KB
  __shared__ unsigned lbuf_n[kPmax];          // 12.8 KB
  __shared__ int he[kNCE], se[kNCE];          // cur counter / global shift (edge)
  __shared__ int hn[kNCN], sn_[kNCN];         // cur counter / global shift (node)
  __shared__ int wtot[4];
  const int tid = threadIdx.x;
  // fused feature conversion (grid-stride over uint4 groups of 8 floats)
  {
    const int n8 = n_feat >> 3;
    for (int t = blockIdx.x * 256 + tid; t < n8; t += gridDim.x * 256) {
      long long i = (long long)t * 8;
      const float4 v0 = *(const float4*)(feat + i);
      const float4 v1 = *(const float4*)(feat + i + 4);
      uint4 o;
      o.x = bfpack(v0.x, v0.y); o.y = bfpack(v0.z, v0.w);
      o.z = bfpack(v1.x, v1.y); o.w = bfpack(v1.z, v1.w);
      *(uint4*)(feat_bf + (i >> 1)) = o;
    }
  }
  const int per_block = (n_pairs + gridDim.x - 1) / gridDim.x;
  const int s = blockIdx.x * per_block;
  const int e = min(s + per_block, n_pairs);
  const int cnt = max(e - s, 0);              // <= kPmax by grid sizing
  for (int i = tid; i < kNCE; i += 256) he[i] = 0;
  for (int i = tid; i < kNCN; i += 256) hn[i] = 0;
  __syncthreads();
  // pass 1: local histograms for both keyings
  for (int i = s + tid; i < e; i += 256) {
    atomicAdd(&he[hedge_idx[i] >> 7], 1);
    atomicAdd(&hn[node_idx[i] >> 9], 1);
  }
  __syncthreads();
  const int lane = tid & 63, wid = tid >> 6;
  // scan edge hist (157 bins <= 256 threads): lofs = local exclusive prefix
  {
    int v = (tid < kNCE) ? he[tid] : 0;
    int x = v;
#pragma unroll
    for (int d = 1; d < 64; d <<= 1) {
      int y = __shfl_up(x, d, 64);
      if (lane >= d) x += y;
    }
    if (lane == 63) wtot[wid] = x;
    __syncthreads();
    int add = 0;
    for (int w = 0; w < wid; ++w) add += wtot[w];
    if (tid < kNCE) {
      int lofs = x + add - v;
      int base = (v > 0) ? atomicAdd(&gcnt_e[tid], v) : 0;
      se[tid] = base - lofs;   // pe = se[b] + lds_slot
      he[tid] = lofs;          // reuse as placement cursor
    }
  }
  __syncthreads();             // wtot reuse barrier
  // scan node hist (196 bins <= 256 threads)
  {
    int v = (tid < kNCN) ? hn[tid] : 0;
    int x = v;
#pragma unroll
    for (int d = 1; d < 64; d <<= 1) {
      int y = __shfl_up(x, d, 64);
      if (lane >= d) x += y;
    }
    if (lane == 63) wtot[wid] = x;
    __syncthreads();
    int add = 0;
    for (int w = 0; w < wid; ++w) add += wtot[w];
    if (tid < kNCN) {
      int lofs = x + add - v;
      int base = (v > 0) ? atomicAdd(&gcnt_n[tid], v) : 0;
      sn_[tid] = base - lofs;
      hn[tid] = lofs;
    }
  }
  __syncthreads();
  // pass 2: block-local counting-sort placement into LDS.
  // full pair packs in 32b: n < 2^17, h < 2^15.
  for (int i = s + tid; i < e; i += 256) {
    const unsigned n = (unsigned)node_idx[i];
    const unsigned h = (unsigned)hedge_idx[i];
    const int be = (int)(h >> 7);
    const int p = atomicAdd(&he[be], 1);
    lbuf_e[p] = (n << 15) | h;
    const int bn = (int)(n >> 9);
    const int q = atomicAdd(&hn[bn], 1);
    lbuf_n[q] = (h << 17) | n;
  }
  __syncthreads();
  // writeback: consecutive LDS slots within a bucket run -> consecutive global
  // addresses (coalesced, full lines, one XCD per run)
  for (int i = tid; i < cnt; i += 256) {
    const unsigned v = lbuf_e[i];
    const int h = (int)(v & 0x7FFFu);
    const int n = (int)(v >> 15);
    const int b = h >> 7;
    const int pe = se[b] + i;
    if (pe < kCapCE) buf_e[(long long)b * kCapCE + pe] = (n << 7) | (h & 127);
  }
  for (int i = tid; i < cnt; i += 256) {
    const unsigned v = lbuf_n[i];
    const int n = (int)(v & 0x1FFFFu);
    const int h = (int)(v >> 17);
    const int b = n >> 9;
    const int pn = sn_[b] + i;
    if (pn < kCapCN) buf_n[(long long)b * kCapCN + pn] = (h << 9) | (n & 511);
  }
}

// ---------- L2: sort each coarse bucket by low key bits, in place; emit segs ----------
// blocks [0,kNCE): edge buckets (128 bins); [kNCE, kNCE+kNCN): node buckets (512 bins).
// 1024 threads: halves every serial sweep vs 512 (353 blocks, 1.4/CU imbalance).
__global__ __launch_bounds__(1024) void subsort_kernel(
    int* __restrict__ buf_e, const int* __restrict__ gcnt_e, int* __restrict__ seg_e,
    int* __restrict__ buf_n, const int* __restrict__ gcnt_n, int* __restrict__ seg_n) {
  __shared__ int sbuf[kCapCE];       // 45 KB
  __shared__ int bins[513];
  __shared__ int cur[512];
  __shared__ int segs[513];
  __shared__ int wtot[16];
  const int tid = threadIdx.x;
  int nbins, shift, cnt; int* src; int* segout;
  if (blockIdx.x < kNCE) {
    int cb = blockIdx.x; nbins = 128; shift = 7;
    src = buf_e + (long long)cb * kCapCE;
    cnt = min(gcnt_e[cb], kCapCE);
    segout = seg_e + cb * 129;
  } else {
    int cb = blockIdx.x - kNCE; nbins = 512; shift = 9;
    src = buf_n + (long long)cb * kCapCN;
    cnt = min(gcnt_n[cb], kCapCN);
    segout = seg_n + cb * 513;
  }
  const int mask = nbins - 1;
  for (int i = tid; i < nbins; i += 1024) bins[i] = 0;
  __syncthreads();
  for (int i = tid; i < cnt; i += 1024) atomicAdd(&bins[src[i] & mask], 1);
  __syncthreads();
  // hierarchical exclusive scan of bins[0..nbins) (16 waves of 64)
  const int lane = tid & 63, wid = tid >> 6;
  int v = (tid < nbins) ? bins[tid] : 0;
  int x = v;
#pragma unroll
  for (int d = 1; d < 64; d <<= 1) {
    int y = __shfl_up(x, d, 64);
    if (lane >= d) x += y;
  }
  if (lane == 63) wtot[wid] = x;
  __syncthreads();
  int add = 0;
  for (int w = 0; w < wid; ++w) add += wtot[w];
  if (tid < nbins) { segs[tid + 1] = x + add; cur[tid] = x + add - v; }
  if (tid == 0) segs[0] = 0;
  __syncthreads();
  for (int i = tid; i < cnt; i += 1024) {
    int p = src[i];
    int r = atomicAdd(&cur[p & mask], 1);
    sbuf[r] = p >> shift;              // payload only: sorted adjacency
  }
  __syncthreads();
  for (int i = tid; i < cnt; i += 1024) src[i] = sbuf[i];   // coalesced writeback
  for (int j = tid; j <= nbins; j += 1024) segout[j] = segs[j];
}

// ---------- gather features -> mean -> @ W.T fused, write t_edge bf16 ----------
// 256 thr / 16 hedges per block. The gather phase is fabric-bound (VALUBusy 24%);
// the per-block 16x128 @ 128x128 GEMM rides under other blocks' memory stalls,
// eliminating the separate edge_linear dispatch (10 MB traffic + launch).
__global__ __launch_bounds__(256) void gather_edge_fused(
    const unsigned* __restrict__ feat_bf, const int* __restrict__ buf_e,
    const int* __restrict__ seg_e, const float* __restrict__ W,
    unsigned* __restrict__ t_edge, int n_hedges) {
  __shared__ int ebuf[kSliceE4];           // 6.6 KB
  __shared__ int segl[17];
  __shared__ unsigned Wt2[kD * kWRow];     // 34.8 KB: word j of row k = W^T[k][2j..2j+1]
  __shared__ float hrow[16][132];          // 8.4 KB (pad 132 -> group-conflict-free)
  const int b = blockIdx.x;                // 16 hedges per block
  const int tid = threadIdx.x;
  const int h0 = b * 16;
  const int cb = h0 >> 7, j0 = h0 & 127;
  if (tid < 17) segl[tid] = seg_e[cb * 129 + j0 + tid];
  // stage Wt2 (bf16-packed W^T) — overlaps with segl/ebuf staging
  for (int i = tid; i < kD * 64; i += 256) {
    int k = i & 127, j = i >> 7;
    float c0 = W[(2 * j) * kD + k];
    float c1 = W[(2 * j + 1) * kD + k];
    Wt2[k * kWRow + j] = bfpack(c0, c1);
  }
  __syncthreads();
  const int sbase = segl[0];
  const int n_sl = min(segl[16] - sbase, kSliceE4);
  const int* src = buf_e + (long long)cb * kCapCE + sbase;
  for (int i = tid; i < n_sl; i += 256) ebuf[i] = src[i];
  __syncthreads();
  const int g = tid >> 4, lane = tid & 15, cw = lane * 4;
  const int gh = h0 + g;
  float a[8] = {}, a2[8] = {};
  int deg = 0;
  if (gh < n_hedges) {
    deg = segl[g + 1] - segl[g];
    const int s0 = min(segl[g] - sbase, n_sl);
    const int e0 = min(segl[g + 1] - sbase, n_sl);
    int j = s0;
    const int jend8 = s0 + ((e0 - s0) & ~7);
    if (j < jend8) {
      uint4 A0 = *(const uint4*)(feat_bf + (long long)ebuf[j] * 64 + cw);
      uint4 A1 = *(const uint4*)(feat_bf + (long long)ebuf[j + 1] * 64 + cw);
      uint4 A2 = *(const uint4*)(feat_bf + (long long)ebuf[j + 2] * 64 + cw);
      uint4 A3 = *(const uint4*)(feat_bf + (long long)ebuf[j + 3] * 64 + cw);
      uint4 A4 = *(const uint4*)(feat_bf + (long long)ebuf[j + 4] * 64 + cw);
      uint4 A5 = *(const uint4*)(feat_bf + (long long)ebuf[j + 5] * 64 + cw);
      uint4 A6 = *(const uint4*)(feat_bf + (long long)ebuf[j + 6] * 64 + cw);
      uint4 A7 = *(const uint4*)(feat_bf + (long long)ebuf[j + 7] * 64 + cw);
      j += 8;
      for (; j < jend8; j += 8) {
        uint4 B0 = *(const uint4*)(feat_bf + (long long)ebuf[j] * 64 + cw);
        uint4 B1 = *(const uint4*)(feat_bf + (long long)ebuf[j + 1] * 64 + cw);
        uint4 B2 = *(const uint4*)(feat_bf + (long long)ebuf[j + 2] * 64 + cw);
        uint4 B3 = *(const uint4*)(feat_bf + (long long)ebuf[j + 3] * 64 + cw);
        uint4 B4 = *(const uint4*)(feat_bf + (long long)ebuf[j + 4] * 64 + cw);
        uint4 B5 = *(const uint4*)(feat_bf + (long long)ebuf[j + 5] * 64 + cw);
        uint4 B6 = *(const uint4*)(feat_bf + (long long)ebuf[j + 6] * 64 + cw);
        uint4 B7 = *(const uint4*)(feat_bf + (long long)ebuf[j + 7] * 64 + cw);
        bf8_acc(A0, a); bf8_acc(A1, a2); bf8_acc(A2, a); bf8_acc(A3, a2);
        bf8_acc(A4, a); bf8_acc(A5, a2); bf8_acc(A6, a); bf8_acc(A7, a2);
        A0 = B0; A1 = B1; A2 = B2; A3 = B3;
        A4 = B4; A5 = B5; A6 = B6; A7 = B7;
      }
      bf8_acc(A0, a); bf8_acc(A1, a2); bf8_acc(A2, a); bf8_acc(A3, a2);
      bf8_acc(A4, a); bf8_acc(A5, a2); bf8_acc(A6, a); bf8_acc(A7, a2);
    }
    for (; j < e0; ++j) {
      uint4 v = *(const uint4*)(feat_bf + (long long)ebuf[j] * 64 + cw);
      bf8_acc(v, a);
    }
  }
  {
    const float inv = 1.0f / fmaxf((float)deg, 1.0f);
    float4 r0, r1;
    r0.x = (a[0] + a2[0]) * inv; r0.y = (a[1] + a2[1]) * inv;
    r0.z = (a[2] + a2[2]) * inv; r0.w = (a[3] + a2[3]) * inv;
    r1.x = (a[4] + a2[4]) * inv; r1.y = (a[5] + a2[5]) * inv;
    r1.z = (a[6] + a2[6]) * inv; r1.w = (a[7] + a2[7]) * inv;
    *(float4*)(&hrow[g][lane * 8]) = r0;
    *(float4*)(&hrow[g][lane * 8 + 4]) = r1;
  }
  __syncthreads();
  // GEMM: out[g][c8*8 + q] = sum_k hrow[g][k] * W[c8*8+q][k]
  float acc[8] = {};
#pragma unroll 2
  for (int k = 0; k < kD; ++k) {
    const uint4 wp = *(const uint4*)(&Wt2[k * kWRow + lane * 4]);
    const float hk = hrow[g][k];
    acc[0] = fmaf(hk, u2f(wp.x << 16), acc[0]);
    acc[1] = fmaf(hk, u2f(wp.x & 0xFFFF0000u), acc[1]);
    acc[2] = fmaf(hk, u2f(wp.y << 16), acc[2]);
    acc[3] = fmaf(hk, u2f(wp.y & 0xFFFF0000u), acc[3]);
    acc[4] = fmaf(hk, u2f(wp.z << 16), acc[4]);
    acc[5] = fmaf(hk, u2f(wp.z & 0xFFFF0000u), acc[5]);
    acc[6] = fmaf(hk, u2f(wp.w << 16), acc[6]);
    acc[7] = fmaf(hk, u2f(wp.w & 0xFFFF0000u), acc[7]);
  }
  if (gh < n_hedges) {
    uint4 o;
    o.x = bfpack(acc[0], acc[1]);
    o.y = bfpack(acc[2], acc[3]);
    o.z = bfpack(acc[4], acc[5]);
    o.w = bfpack(acc[6], acc[7]);
    *(uint4*)(t_edge + (long long)gh * 64 + cw) = o;
  }
}

// ---------- gather t_edge -> fp32 out (mean) + bias, MLP-pipelined ----------
// 256 thr / 64 nodes per block (16 groups x 16 lanes, 4 nodes per group).
__global__ __launch_bounds__(256) void gather_node_v4(
    const unsigned* __restrict__ t_edge, const int* __restrict__ buf_n,
    const int* __restrict__ seg_n, const float* __restrict__ bias,
    float* __restrict__ out, int n_nodes) {
  __shared__ int ebuf[kSliceN4];
  __shared__ int segl[65];
  const int b = blockIdx.x;            // 64 nodes per block
  const int tid = threadIdx.x;
  const int n0 = b * 64;
  const int cb = n0 >> 9, j0 = n0 & 511;
  if (tid < 65) segl[tid] = seg_n[cb * 513 + j0 + tid];
  __syncthreads();
  const int sbase = segl[0];
  const int n_sl = min(segl[64] - sbase, kSliceN4);
  const int* src = buf_n + (long long)cb * kCapCN + sbase;
  for (int i = tid; i < n_sl; i += 256) ebuf[i] = src[i];
  __syncthreads();
  const int g = tid >> 4, lane = tid & 15, cw = lane * 4;
  const float4 b0 = *(const float4*)(bias + lane * 8);
  const float4 b1 = *(const float4*)(bias + lane * 8 + 4);
  for (int nl = g; nl < 64; nl += 16) {
    int gn = n0 + nl;
    if (gn >= n_nodes) continue;
    const int deg = segl[nl + 1] - segl[nl];
    const int s0 = min(segl[nl] - sbase, n_sl);
    const int e0 = min(segl[nl + 1] - sbase, n_sl);
    float a[8] = {}, a2[8] = {};
    int j = s0;
    const int jend8 = s0 + ((e0 - s0) & ~7);
    if (j < jend8) {
      uint4 A0 = *(const uint4*)(t_edge + (long long)ebuf[j] * 64 + cw);
      uint4 A1 = *(const uint4*)(t_edge + (long long)ebuf[j + 1] * 64 + cw);
      uint4 A2 = *(const uint4*)(t_edge + (long long)ebuf[j + 2] * 64 + cw);
      uint4 A3 = *(const uint4*)(t_edge + (long long)ebuf[j + 3] * 64 + cw);
      uint4 A4 = *(const uint4*)(t_edge + (long long)ebuf[j + 4] * 64 + cw);
      uint4 A5 = *(const uint4*)(t_edge + (long long)ebuf[j + 5] * 64 + cw);
      uint4 A6 = *(const uint4*)(t_edge + (long long)ebuf[j + 6] * 64 + cw);
      uint4 A7 = *(const uint4*)(t_edge + (long long)ebuf[j + 7] * 64 + cw);
      j += 8;
      for (; j < jend8; j += 8) {
        uint4 B0 = *(const uint4*)(t_edge + (long long)ebuf[j] * 64 + cw);
        uint4 B1 = *(const uint4*)(t_edge + (long long)ebuf[j + 1] * 64 + cw);
        uint4 B2 = *(const uint4*)(t_edge + (long long)ebuf[j + 2] * 64 + cw);
        uint4 B3 = *(const uint4*)(t_edge + (long long)ebuf[j + 3] * 64 + cw);
        uint4 B4 = *(const uint4*)(t_edge + (long long)ebuf[j + 4] * 64 + cw);
        uint4 B5 = *(const uint4*)(t_edge + (long long)ebuf[j + 5] * 64 + cw);
        uint4 B6 = *(const uint4*)(t_edge + (long long)ebuf[j + 6] * 64 + cw);
        uint4 B7 = *(const uint4*)(t_edge + (long long)ebuf[j + 7] * 64 + cw);
        bf8_acc(A0, a); bf8_acc(A1, a2); bf8_acc(A2, a); bf8_acc(A3, a2);
        bf8_acc(A4, a); bf8_acc(A5, a2); bf8_acc(A6, a); bf8_acc(A7, a2);
        A0 = B0; A1 = B1; A2 = B2; A3 = B3;
        A4 = B4; A5 = B5; A6 = B6; A7 = B7;
      }
      bf8_acc(A0, a); bf8_acc(A1, a2); bf8_acc(A2, a); bf8_acc(A3, a2);
      bf8_acc(A4, a); bf8_acc(A5, a2); bf8_acc(A6, a); bf8_acc(A7, a2);
    }
    for (; j < e0; ++j) {
      uint4 v = *(const uint4*)(t_edge + (long long)ebuf[j] * 64 + cw);
      bf8_acc(v, a);
    }
#pragma unroll
    for (int t = 0; t < 8; ++t) a[t] += a2[t];
    float inv = 1.0f / fmaxf((float)deg, 1.0f);
    float4 o0, o1;
    o0.x = fmaf(a[0], inv, b0.x); o0.y = fmaf(a[1], inv, b0.y);
    o0.z = fmaf(a[2], inv, b0.z); o0.w = fmaf(a[3], inv, b0.w);
    o1.x = fmaf(a[4], inv, b1.x); o1.y = fmaf(a[5], inv, b1.y);
    o1.z = fmaf(a[6], inv, b1.z); o1.w = fmaf(a[7], inv, b1.w);
    float* op = out + (long long)gn * kD + lane * 8;
    *(float4*)op = o0;
    *(float4*)(op + 4) = o1;
  }
}

extern "C" void kernel_launch(void* const* d_in, const int* in_sizes, int n_in,
                              void* d_out, int out_size, void* d_ws, size_t ws_size,
                              hipStream_t stream) {
  const float* feat      = (const float*)d_in[0];
  const float* W         = (const float*)d_in[1];
  const float* b         = (const float*)d_in[2];
  const int*   node_idx  = (const int*)d_in[3];
  const int*   hedge_idx = (const int*)d_in[4];

  const int n_pairs  = in_sizes[3];
  const int n_nodes  = in_sizes[0] / kD;
  const int n_hedges = kHedges;
  const int n_feat   = in_sizes[0];

  // feat_bf lives in d_out's buffer (25.6 of 51.2 MB; dead until final kernel)
  unsigned* feat_bf = (unsigned*)d_out;

  // Workspace (~20 MB)
  const int n_rows_pad = ((n_hedges + 63) / 64) * 64;          // 20032
  unsigned* t_edge = (unsigned*)d_ws;                          // 20032*64 words
  int* buf_e = (int*)(t_edge + (size_t)n_rows_pad * 64);       // kNCE*kCapCE
  int* buf_n = buf_e + (size_t)kNCE * kCapCE;                  // kNCN*kCapCN
  int* seg_e = buf_n + (size_t)kNCN * kCapCN;                  // kNCE*129
  int* seg_n = seg_e + (size_t)kNCE * 129;                     // kNCN*513
  int* gcnt_e = seg_n + (size_t)kNCN * 513;                    // kNCE
  int* gcnt_n = gcnt_e + kNCE;                                 // kNCN

  hipMemsetAsync(gcnt_e, 0, (size_t)(kNCE + kNCN) * sizeof(int), stream);

  // grid sized so per_block = ceil(n_pairs/grid) <= kPmax (LDS staging cap)
  int pgrid = (n_pairs + kPmax - 1) / kPmax;
  if (pgrid < 512) pgrid = 512;

  partition_coarse<<<pgrid, 256, 0, stream>>>(
      feat, feat_bf, n_feat,
      node_idx, hedge_idx, n_pairs, gcnt_e, buf_e, gcnt_n, buf_n);

  subsort_kernel<<<kNCE + kNCN, 1024, 0, stream>>>(
      buf_e, gcnt_e, seg_e, buf_n, gcnt_n, seg_n);

  gather_edge_fused<<<(n_hedges + 15) / 16, 256, 0, stream>>>(
      feat_bf, buf_e, seg_e, W, t_edge, n_hedges);

  gather_node_v4<<<(n_nodes + 63) / 64, 256, 0, stream>>>(
      t_edge, buf_n, seg_n, b, (float*)d_out, n_nodes);
}